// Round 3
// baseline (259.365 us; speedup 1.0000x reference)
//
#include <hip/hip_runtime.h>
#include <hip/hip_bf16.h>
#include <math.h>

// ---------- types ----------
typedef __bf16 bf16x8 __attribute__((ext_vector_type(8)));
typedef float  f32x4  __attribute__((ext_vector_type(4)));

#define B_ROWS 8192
#define HSZ    1024

// async global->LDS, 16B per lane. LDS dest must be wave-uniform-base + lane*16.
#define GLOAD16(gsrc, ldst)                                                          \
  __builtin_amdgcn_global_load_lds((const __attribute__((address_space(1))) void*)(gsrc), \
                                   (__attribute__((address_space(3))) void*)(ldst),  \
                                   16, 0, 0)

__device__ inline unsigned short f2bf(float f) {
  union { float f; unsigned u; } x; x.f = f;
  unsigned r = x.u + 0x7fffu + ((x.u >> 16) & 1u);   // RNE
  return (unsigned short)(r >> 16);
}

__device__ inline void store4bf(unsigned short* p, float4 v) {
  ushort4 u;
  u.x = f2bf(v.x); u.y = f2bf(v.y); u.z = f2bf(v.z); u.w = f2bf(v.w);
  *(ushort4*)p = u;  // 8B store
}

__device__ inline float sigm(float x) { return 1.0f / (1.0f + __expf(-x)); }

// ---------- kernel 0: fp32 -> bf16 conversion + T precompute ----------
__global__ void k_convert(const float* __restrict__ inp,   // [8192][1025]
                          const float* __restrict__ h,     // [8192][1024]
                          const float* __restrict__ Wl,    // [4096][2048]
                          const float* __restrict__ Wd,    // [1024][1024]
                          unsigned short* __restrict__ comb, // [8192][2048] bf16 bits (cols 0..1023 = x)
                          unsigned short* __restrict__ Wlb,  // [4096][2048]
                          unsigned short* __restrict__ hb,   // [8192][1024]
                          unsigned short* __restrict__ Wdb,  // [1024][1024]
                          float* __restrict__ Tm1) {         // [8192] = T-1
  const long stride = (long)gridDim.x * blockDim.x;
  const long tid0 = (long)blockIdx.x * blockDim.x + threadIdx.x;

  // h_cur -> hb
  for (long i = tid0; i < (long)B_ROWS * HSZ / 4; i += stride) {
    float4 v = ((const float4*)h)[i];
    store4bf(hb + i * 4, v);
  }
  // x -> comb[:, :1024]   (source rows have stride 1025)
  for (long i = tid0; i < (long)B_ROWS * HSZ / 4; i += stride) {
    long e = i * 4; long b = e >> 10; long c = e & 1023;
    float4 v = *(const float4*)(inp + b * 1025 + c);
    store4bf(comb + b * 2048 + c, v);
  }
  // W_layers -> Wlb
  for (long i = tid0; i < 4096L * 2048 / 4; i += stride) {
    float4 v = ((const float4*)Wl)[i];
    store4bf(Wlb + i * 4, v);
  }
  // W_desc -> Wdb
  for (long i = tid0; i < 1024L * 1024 / 4; i += stride) {
    float4 v = ((const float4*)Wd)[i];
    store4bf(Wdb + i * 4, v);
  }
  // T - 1
  for (long i = tid0; i < B_ROWS; i += stride) {
    float dt = inp[i * 1025 + 1024];
    Tm1[i] = 1.0f / logf(dt + 2.7183f) - 1.0f;
  }
}

// ---------- kernel 1: C_ST GEMM (8192x1024x1024) + h_adj epilogue ----------
// C[b][j] = tanh(sum_k hb[b][k]*Wdb[j][k] + bd[j]); h_adj = h + Tm1[b]*C_ST -> comb[:,1024+j]
__global__ void k_gemm1(const unsigned short* __restrict__ A,   // hb  [8192][1024]
                        const unsigned short* __restrict__ Bm,  // Wdb [1024][1024]
                        const float* __restrict__ h,            // h_cur f32
                        const float* __restrict__ bd,           // b_desc [1024]
                        const float* __restrict__ Tm1,
                        unsigned short* __restrict__ comb) {
  const int K = 1024;
  __shared__ __align__(16) unsigned short As[128 * 32];
  __shared__ __align__(16) unsigned short Bs[128 * 32];
  const int tid = threadIdx.x;
  const int lane = tid & 63;
  const int wave = tid >> 6;
  const int wr = wave >> 1, wc = wave & 1;
  const int bRow = blockIdx.x;    // 0..63
  const int bCol = blockIdx.y;    // 0..7

  const int sRow = tid >> 2;        // 0..63
  const int sK = (tid & 3) * 8;     // 0,8,16,24
  const unsigned short* aSrc0 = A + (long)(bRow * 128 + sRow) * K + sK;
  const unsigned short* aSrc1 = A + (long)(bRow * 128 + 64 + sRow) * K + sK;
  const unsigned short* bSrc0 = Bm + (long)(bCol * 128 + sRow) * K + sK;
  const unsigned short* bSrc1 = Bm + (long)(bCol * 128 + 64 + sRow) * K + sK;
  unsigned short* aDst0 = As + tid * 8;
  unsigned short* aDst1 = As + 2048 + tid * 8;
  unsigned short* bDst0 = Bs + tid * 8;
  unsigned short* bDst1 = Bs + 2048 + tid * 8;

  f32x4 acc[4][4] = {};
  const int fr = lane & 15, fk = (lane >> 4) * 8;

  for (int k0 = 0; k0 < K; k0 += 32) {
    GLOAD16(aSrc0 + k0, aDst0);
    GLOAD16(aSrc1 + k0, aDst1);
    GLOAD16(bSrc0 + k0, bDst0);
    GLOAD16(bSrc1 + k0, bDst1);
    __syncthreads();
    bf16x8 a[4], b[4];
#pragma unroll
    for (int m = 0; m < 4; m++) a[m] = *(const bf16x8*)(As + (wr * 64 + m * 16 + fr) * 32 + fk);
#pragma unroll
    for (int n = 0; n < 4; n++) b[n] = *(const bf16x8*)(Bs + (wc * 64 + n * 16 + fr) * 32 + fk);
#pragma unroll
    for (int m = 0; m < 4; m++)
#pragma unroll
      for (int n = 0; n < 4; n++)
        acc[m][n] = __builtin_amdgcn_mfma_f32_16x16x32_bf16(a[m], b[n], acc[m][n], 0, 0, 0);
    __syncthreads();
  }

  const int cr = (lane >> 4) * 4;
  const int cc = lane & 15;
#pragma unroll
  for (int m = 0; m < 4; m++)
#pragma unroll
    for (int n = 0; n < 4; n++) {
      const int col = bCol * 128 + wc * 64 + n * 16 + cc;
#pragma unroll
      for (int r = 0; r < 4; r++) {
        const int row = bRow * 128 + wr * 64 + m * 16 + cr + r;
        float v = acc[m][n][r] + bd[col];
        float cst = tanhf(v);
        float hadj = h[(long)row * HSZ + col] + Tm1[row] * cst;
        comb[(long)row * 2048 + 1024 + col] = f2bf(hadj);
      }
    }
}

// ---------- kernel 2: gates GEMM (8192 x [4x1024] x 2048) + LSTM epilogue ----------
// B-tile: 128 rows = 4 gates x 32 j-cols; frag n == gate n so each thread holds i,f,o,g.
__global__ void k_gemm2(const unsigned short* __restrict__ A,   // comb [8192][2048]
                        const unsigned short* __restrict__ Bm,  // Wlb  [4096][2048]
                        const float* __restrict__ bl,           // b_layers [4096]
                        const float* __restrict__ c_cur,        // f32 [8192][1024]
                        float* __restrict__ out) {              // h_next | c_next (f32!)
  const int K = 2048;
  __shared__ __align__(16) unsigned short As[128 * 32];
  __shared__ __align__(16) unsigned short Bs[128 * 32];
  const int tid = threadIdx.x;
  const int lane = tid & 63;
  const int wave = tid >> 6;
  const int wr = wave >> 1, wc = wave & 1;   // wr: row half, wc: j-col half (16 cols each)
  const int bRow = blockIdx.x;    // 0..63
  const int bj = blockIdx.y;      // 0..31  (32 j-cols per block)

  const int sRow = tid >> 2;      // 0..63
  const int sK = (tid & 3) * 8;
  // B-tile local row rl: gate = rl>>5, c = rl&31 -> global W row = gate*1024 + bj*32 + c
  const int rl0 = sRow, rl1 = 64 + sRow;
  const unsigned short* aSrc0 = A + (long)(bRow * 128 + sRow) * K + sK;
  const unsigned short* aSrc1 = A + (long)(bRow * 128 + 64 + sRow) * K + sK;
  const unsigned short* bSrc0 = Bm + (long)((rl0 >> 5) * 1024 + bj * 32 + (rl0 & 31)) * K + sK;
  const unsigned short* bSrc1 = Bm + (long)((rl1 >> 5) * 1024 + bj * 32 + (rl1 & 31)) * K + sK;
  unsigned short* aDst0 = As + tid * 8;
  unsigned short* aDst1 = As + 2048 + tid * 8;
  unsigned short* bDst0 = Bs + tid * 8;
  unsigned short* bDst1 = Bs + 2048 + tid * 8;

  f32x4 acc[4][4] = {};   // [m][gate]
  const int fr = lane & 15, fk = (lane >> 4) * 8;

  for (int k0 = 0; k0 < K; k0 += 32) {
    GLOAD16(aSrc0 + k0, aDst0);
    GLOAD16(aSrc1 + k0, aDst1);
    GLOAD16(bSrc0 + k0, bDst0);
    GLOAD16(bSrc1 + k0, bDst1);
    __syncthreads();
    bf16x8 a[4], b[4];
#pragma unroll
    for (int m = 0; m < 4; m++) a[m] = *(const bf16x8*)(As + (wr * 64 + m * 16 + fr) * 32 + fk);
#pragma unroll
    for (int n = 0; n < 4; n++) b[n] = *(const bf16x8*)(Bs + (n * 32 + wc * 16 + fr) * 32 + fk);
#pragma unroll
    for (int m = 0; m < 4; m++)
#pragma unroll
      for (int n = 0; n < 4; n++)
        acc[m][n] = __builtin_amdgcn_mfma_f32_16x16x32_bf16(a[m], b[n], acc[m][n], 0, 0, 0);
    __syncthreads();
  }

  const int cr = (lane >> 4) * 4;
  const int cc = lane & 15;
  const int j = bj * 32 + wc * 16 + cc;         // 0..1023
#pragma unroll
  for (int m = 0; m < 4; m++) {
#pragma unroll
    for (int r = 0; r < 4; r++) {
      const int row = bRow * 128 + wr * 64 + m * 16 + cr + r;
      float iv = sigm(acc[m][0][r] + bl[j]);
      float fv = sigm(acc[m][1][r] + bl[1024 + j]);
      float ov = sigm(acc[m][2][r] + bl[2048 + j]);
      float gv = tanhf(acc[m][3][r] + bl[3072 + j]);
      float cn = fv * c_cur[(long)row * HSZ + j] + iv * gv;
      float hn = ov * tanhf(cn);
      out[(long)row * HSZ + j] = hn;                               // h_next (f32)
      out[(long)B_ROWS * HSZ + (long)row * HSZ + j] = cn;          // c_next (f32)
    }
  }
}

// ---------- launch ----------
extern "C" void kernel_launch(void* const* d_in, const int* in_sizes, int n_in,
                              void* d_out, int out_size, void* d_ws, size_t ws_size,
                              hipStream_t stream) {
  const float* inp = (const float*)d_in[0];   // input_tensor [8192][1025]
  const float* h   = (const float*)d_in[1];   // h_cur
  const float* c   = (const float*)d_in[2];   // c_cur
  const float* Wl  = (const float*)d_in[3];   // W_layers [4096][2048]
  const float* bl  = (const float*)d_in[4];   // b_layers [4096]
  const float* Wd  = (const float*)d_in[5];   // W_desc [1024][1024]
  const float* bd  = (const float*)d_in[6];   // b_desc [1024]

  char* ws = (char*)d_ws;
  unsigned short* comb = (unsigned short*)(ws);               // 33,554,432 B
  unsigned short* Wlb  = (unsigned short*)(ws + 33554432);    // 16,777,216 B
  unsigned short* hb   = (unsigned short*)(ws + 50331648);    // 16,777,216 B
  unsigned short* Wdb  = (unsigned short*)(ws + 67108864);    //  2,097,152 B
  float*          Tm1  = (float*)(ws + 69206016);             //     32,768 B
  float*          out  = (float*)d_out;                       // f32 outputs!

  hipLaunchKernelGGL(k_convert, dim3(2048), dim3(256), 0, stream,
                     inp, h, Wl, Wd, comb, Wlb, hb, Wdb, Tm1);
  hipLaunchKernelGGL(k_gemm1, dim3(64, 8), dim3(256), 0, stream,
                     hb, Wdb, h, bd, Tm1, comb);
  hipLaunchKernelGGL(k_gemm2, dim3(64, 32), dim3(256), 0, stream,
                     comb, Wlb, bl, c, out);
}

// Round 4
// 242.987 us; speedup vs baseline: 1.0674x; 1.0674x over previous
//
#include <hip/hip_runtime.h>
#include <hip/hip_bf16.h>
#include <math.h>

// ---------- types ----------
typedef __bf16 bf16x8 __attribute__((ext_vector_type(8)));
typedef float  f32x4  __attribute__((ext_vector_type(4)));

#define B_ROWS 8192
#define HSZ    1024

// async global->LDS, 16B per lane. LDS dest must be wave-uniform-base + lane*16.
#define GLOAD16(gsrc, ldst)                                                          \
  __builtin_amdgcn_global_load_lds((const __attribute__((address_space(1))) void*)(gsrc), \
                                   (__attribute__((address_space(3))) void*)(ldst),  \
                                   16, 0, 0)

__device__ inline unsigned short f2bf(float f) {
  union { float f; unsigned u; } x; x.f = f;
  unsigned r = x.u + 0x7fffu + ((x.u >> 16) & 1u);   // RNE
  return (unsigned short)(r >> 16);
}

__device__ inline void store4bf(unsigned short* p, float4 v) {
  ushort4 u;
  u.x = f2bf(v.x); u.y = f2bf(v.y); u.z = f2bf(v.z); u.w = f2bf(v.w);
  *(ushort4*)p = u;  // 8B store
}

__device__ inline float sigm(float x) { return 1.0f / (1.0f + __expf(-x)); }

// ---------- kernel 0: fp32 -> bf16 conversion + T precompute ----------
__global__ void k_convert(const float* __restrict__ inp,   // [8192][1025]
                          const float* __restrict__ h,     // [8192][1024]
                          const float* __restrict__ Wl,    // [4096][2048]
                          const float* __restrict__ Wd,    // [1024][1024]
                          unsigned short* __restrict__ comb, // [8192][2048] bf16 bits (cols 0..1023 = x)
                          unsigned short* __restrict__ Wlb,  // [4096][2048]
                          unsigned short* __restrict__ hb,   // [8192][1024]
                          unsigned short* __restrict__ Wdb,  // [1024][1024]
                          float* __restrict__ Tm1) {         // [8192] = T-1
  const long stride = (long)gridDim.x * blockDim.x;
  const long tid0 = (long)blockIdx.x * blockDim.x + threadIdx.x;

  for (long i = tid0; i < (long)B_ROWS * HSZ / 4; i += stride) {
    float4 v = ((const float4*)h)[i];
    store4bf(hb + i * 4, v);
  }
  for (long i = tid0; i < (long)B_ROWS * HSZ / 4; i += stride) {
    long e = i * 4; long b = e >> 10; long c = e & 1023;
    float4 v = *(const float4*)(inp + b * 1025 + c);
    store4bf(comb + b * 2048 + c, v);
  }
  for (long i = tid0; i < 4096L * 2048 / 4; i += stride) {
    float4 v = ((const float4*)Wl)[i];
    store4bf(Wlb + i * 4, v);
  }
  for (long i = tid0; i < 1024L * 1024 / 4; i += stride) {
    float4 v = ((const float4*)Wd)[i];
    store4bf(Wdb + i * 4, v);
  }
  for (long i = tid0; i < B_ROWS; i += stride) {
    float dt = inp[i * 1025 + 1024];
    Tm1[i] = 1.0f / logf(dt + 2.7183f) - 1.0f;
  }
}

// ---------- kernel 1: C_ST GEMM (8192x1024x1024) + h_adj epilogue (known-good) ----------
__global__ void k_gemm1(const unsigned short* __restrict__ A,   // hb  [8192][1024]
                        const unsigned short* __restrict__ Bm,  // Wdb [1024][1024]
                        const float* __restrict__ h,            // h_cur f32
                        const float* __restrict__ bd,           // b_desc [1024]
                        const float* __restrict__ Tm1,
                        unsigned short* __restrict__ comb) {
  const int K = 1024;
  __shared__ __align__(16) unsigned short As[128 * 32];
  __shared__ __align__(16) unsigned short Bs[128 * 32];
  const int tid = threadIdx.x;
  const int lane = tid & 63;
  const int wave = tid >> 6;
  const int wr = wave >> 1, wc = wave & 1;
  const int bRow = blockIdx.x;    // 0..63
  const int bCol = blockIdx.y;    // 0..7

  const int sRow = tid >> 2;
  const int sK = (tid & 3) * 8;
  const unsigned short* aSrc0 = A + (long)(bRow * 128 + sRow) * K + sK;
  const unsigned short* aSrc1 = A + (long)(bRow * 128 + 64 + sRow) * K + sK;
  const unsigned short* bSrc0 = Bm + (long)(bCol * 128 + sRow) * K + sK;
  const unsigned short* bSrc1 = Bm + (long)(bCol * 128 + 64 + sRow) * K + sK;
  unsigned short* aDst0 = As + tid * 8;
  unsigned short* aDst1 = As + 2048 + tid * 8;
  unsigned short* bDst0 = Bs + tid * 8;
  unsigned short* bDst1 = Bs + 2048 + tid * 8;

  f32x4 acc[4][4] = {};
  const int fr = lane & 15, fk = (lane >> 4) * 8;

  for (int k0 = 0; k0 < K; k0 += 32) {
    GLOAD16(aSrc0 + k0, aDst0);
    GLOAD16(aSrc1 + k0, aDst1);
    GLOAD16(bSrc0 + k0, bDst0);
    GLOAD16(bSrc1 + k0, bDst1);
    __syncthreads();
    bf16x8 a[4], b[4];
#pragma unroll
    for (int m = 0; m < 4; m++) a[m] = *(const bf16x8*)(As + (wr * 64 + m * 16 + fr) * 32 + fk);
#pragma unroll
    for (int n = 0; n < 4; n++) b[n] = *(const bf16x8*)(Bs + (wc * 64 + n * 16 + fr) * 32 + fk);
#pragma unroll
    for (int m = 0; m < 4; m++)
#pragma unroll
      for (int n = 0; n < 4; n++)
        acc[m][n] = __builtin_amdgcn_mfma_f32_16x16x32_bf16(a[m], b[n], acc[m][n], 0, 0, 0);
    __syncthreads();
  }

  const int cr = (lane >> 4) * 4;
  const int cc = lane & 15;
#pragma unroll
  for (int m = 0; m < 4; m++)
#pragma unroll
    for (int n = 0; n < 4; n++) {
      const int col = bCol * 128 + wc * 64 + n * 16 + cc;
#pragma unroll
      for (int r = 0; r < 4; r++) {
        const int row = bRow * 128 + wr * 64 + m * 16 + cr + r;
        float v = acc[m][n][r] + bd[col];
        float cst = tanhf(v);
        float hadj = h[(long)row * HSZ + col] + Tm1[row] * cst;
        comb[(long)row * 2048 + 1024 + col] = f2bf(hadj);
      }
    }
}

// ---------- kernel 2: gates GEMM, 256x256 tile, ring-4 LDS, counted-vmcnt pipeline ----------
// C = comb[8192][2048] @ Wlb^T (gate-interleaved cols) + fused LSTM epilogue.
// K-tiles of 32; compute tile t from ring[t&3] while staging tile t+3 into ring[(t+3)&3].
// LDS swizzle (64B rows): kbyte ^= ((row>>1)&3)<<4  -> conflict-free ds_read_b128.
#define NT2 64   // 2048/32
__global__ __launch_bounds__(512, 2)
void k_gemm2_8ph(const unsigned short* __restrict__ A,   // comb [8192][2048]
                 const unsigned short* __restrict__ Bm,  // Wlb  [4096][2048]
                 const float* __restrict__ bl,           // b_layers [4096]
                 const float* __restrict__ c_cur,        // f32 [8192][1024]
                 float* __restrict__ out) {              // h_next | c_next (f32)
  // ring[4] buffers: each 32KB = A-tile [256][32] (16KB) | B-tile [256][32] (16KB)
  __shared__ __align__(16) unsigned short lds[4][16384];

  const int tid = threadIdx.x;
  const int lane = tid & 63;
  const int wid = tid >> 6;
  const int wr = wid >> 2;          // 0..1 : row half (128 rows)
  const int wc = wid & 3;           // 0..3 : col quarter (64 local cols = 16 j x 4 gates)

  // XCD-bijective block swizzle (512 blocks, 512%8==0)
  const int bid = blockIdx.x;
  const int swz = (bid & 7) * 64 + (bid >> 3);
  const int bRow = swz & 31;        // 0..31
  const int bCol = swz >> 5;        // 0..15

  // ---- staging addresses (pre-swizzled global source; LDS dest linear) ----
  const int sr = tid >> 2;                 // 0..127 (row within one gload's 128 rows)
  const int swsel = (sr >> 1) & 3;         // same for row sr and sr+128
  const int gk = ((tid & 3) ^ swsel) << 3; // pre-swizzled k-element offset (0,8,16,24 perm)
  const unsigned short* aBase = A + (long)(bRow * 256 + sr) * 2048 + gk;
  // B rows: local row rl -> W_layers row gate*1024 + bCol*64 + jl
  const int rl0 = sr, rl1 = 128 + sr;
  const int grow0 = ((rl0 >> 4) & 3) * 1024 + bCol * 64 + (rl0 >> 6) * 16 + (rl0 & 15);
  const int grow1 = ((rl1 >> 4) & 3) * 1024 + bCol * 64 + (rl1 >> 6) * 16 + (rl1 & 15);
  const unsigned short* bBase0 = Bm + (long)grow0 * 2048 + gk;
  const unsigned short* bBase1 = Bm + (long)grow1 * 2048 + gk;

#define STAGE_A2(tt) { unsigned short* d_ = &lds[(tt) & 3][0] + tid * 8;          \
    GLOAD16(aBase + (long)(tt) * 32, d_);                                          \
    GLOAD16(aBase + 128L * 2048 + (long)(tt) * 32, d_ + 512 * 8); }
#define STAGE_B2(tt) { unsigned short* d_ = &lds[(tt) & 3][8192] + tid * 8;       \
    GLOAD16(bBase0 + (long)(tt) * 32, d_);                                         \
    GLOAD16(bBase1 + (long)(tt) * 32, d_ + 512 * 8); }

  // ---- fragment read offsets (swizzled), in ushort units ----
  const int fr = lane & 15, q = lane >> 4;
  int offA[8], offB[4];
#pragma unroll
  for (int m = 0; m < 8; m++) {
    const int row = wr * 128 + m * 16 + fr;
    offA[m] = row * 32 + ((q ^ ((row >> 1) & 3)) << 3);
  }
#pragma unroll
  for (int n = 0; n < 4; n++) {
    const int row = wc * 64 + n * 16 + fr;
    offB[n] = 8192 + row * 32 + ((q ^ ((row >> 1) & 3)) << 3);
  }

  f32x4 acc[8][4] = {};   // [m][gate]

  // ---- prologue: stage tiles 0,1,2 (12 loads), wait tile 0 (all but 8) ----
  STAGE_A2(0); STAGE_B2(0);
  STAGE_A2(1); STAGE_B2(1);
  STAGE_A2(2); STAGE_B2(2);
  asm volatile("s_waitcnt vmcnt(8)" ::: "memory");
  __builtin_amdgcn_sched_barrier(0);
  __builtin_amdgcn_s_barrier();

  for (int t = 0; t < NT2; ++t) {
    const unsigned short* buf = lds[t & 3];
    // ---- phase A: frags m0-3 + all B; stage A(t+3) ----
    bf16x8 a[4], b[4];
#pragma unroll
    for (int m = 0; m < 4; m++) a[m] = *(const bf16x8*)(buf + offA[m]);
#pragma unroll
    for (int n = 0; n < 4; n++) b[n] = *(const bf16x8*)(buf + offB[n]);
    if (t < NT2 - 3) STAGE_A2(t + 3);
    __builtin_amdgcn_s_barrier();
    asm volatile("s_waitcnt lgkmcnt(0)" ::: "memory");
    __builtin_amdgcn_sched_barrier(0);
    __builtin_amdgcn_s_setprio(1);
#pragma unroll
    for (int m = 0; m < 4; m++)
#pragma unroll
      for (int n = 0; n < 4; n++)
        acc[m][n] = __builtin_amdgcn_mfma_f32_16x16x32_bf16(a[m], b[n], acc[m][n], 0, 0, 0);
    __builtin_amdgcn_s_setprio(0);
    __builtin_amdgcn_s_barrier();
    // ---- phase B: frags m4-7 (B regs reused); stage B(t+3) ----
#pragma unroll
    for (int m = 0; m < 4; m++) a[m] = *(const bf16x8*)(buf + offA[m + 4]);
    if (t < NT2 - 3) STAGE_B2(t + 3);
    __builtin_amdgcn_s_barrier();
    asm volatile("s_waitcnt lgkmcnt(0)" ::: "memory");
    __builtin_amdgcn_sched_barrier(0);
    __builtin_amdgcn_s_setprio(1);
#pragma unroll
    for (int m = 0; m < 4; m++)
#pragma unroll
      for (int n = 0; n < 4; n++)
        acc[m + 4][n] = __builtin_amdgcn_mfma_f32_16x16x32_bf16(a[m], b[n], acc[m + 4][n], 0, 0, 0);
    __builtin_amdgcn_s_setprio(0);
    // ---- counted vmcnt: guarantee tile t+1 resident; keep 2 tiles in flight ----
    if (t < NT2 - 3)       { asm volatile("s_waitcnt vmcnt(8)" ::: "memory"); }
    else if (t == NT2 - 3) { asm volatile("s_waitcnt vmcnt(4)" ::: "memory"); }
    else if (t == NT2 - 2) { asm volatile("s_waitcnt vmcnt(0)" ::: "memory"); }
    __builtin_amdgcn_sched_barrier(0);
    __builtin_amdgcn_s_barrier();
  }

  // ---- fused LSTM epilogue ----
  const int cr = (lane >> 4) * 4;
  const int cc = lane & 15;
  const int j = bCol * 64 + wc * 16 + cc;       // 0..1023
#pragma unroll
  for (int m = 0; m < 8; m++) {
#pragma unroll
    for (int r = 0; r < 4; r++) {
      const int row = bRow * 256 + wr * 128 + m * 16 + cr + r;
      float iv = sigm(acc[m][0][r] + bl[j]);
      float fv = sigm(acc[m][1][r] + bl[1024 + j]);
      float ov = sigm(acc[m][2][r] + bl[2048 + j]);
      float gv = tanhf(acc[m][3][r] + bl[3072 + j]);
      float cn = fv * c_cur[(long)row * HSZ + j] + iv * gv;
      float hn = ov * tanhf(cn);
      out[(long)row * HSZ + j] = hn;                         // h_next
      out[(long)B_ROWS * HSZ + (long)row * HSZ + j] = cn;    // c_next
    }
  }
}

// ---------- launch ----------
extern "C" void kernel_launch(void* const* d_in, const int* in_sizes, int n_in,
                              void* d_out, int out_size, void* d_ws, size_t ws_size,
                              hipStream_t stream) {
  const float* inp = (const float*)d_in[0];   // input_tensor [8192][1025]
  const float* h   = (const float*)d_in[1];   // h_cur
  const float* c   = (const float*)d_in[2];   // c_cur
  const float* Wl  = (const float*)d_in[3];   // W_layers [4096][2048]
  const float* bl  = (const float*)d_in[4];   // b_layers [4096]
  const float* Wd  = (const float*)d_in[5];   // W_desc [1024][1024]
  const float* bd  = (const float*)d_in[6];   // b_desc [1024]

  char* ws = (char*)d_ws;
  unsigned short* comb = (unsigned short*)(ws);               // 33,554,432 B
  unsigned short* Wlb  = (unsigned short*)(ws + 33554432);    // 16,777,216 B
  unsigned short* hb   = (unsigned short*)(ws + 50331648);    // 16,777,216 B
  unsigned short* Wdb  = (unsigned short*)(ws + 67108864);    //  2,097,152 B
  float*          Tm1  = (float*)(ws + 69206016);             //     32,768 B
  float*          out  = (float*)d_out;                       // f32 outputs

  hipLaunchKernelGGL(k_convert, dim3(2048), dim3(256), 0, stream,
                     inp, h, Wl, Wd, comb, Wlb, hb, Wdb, Tm1);
  hipLaunchKernelGGL(k_gemm1, dim3(64, 8), dim3(256), 0, stream,
                     hb, Wdb, h, bd, Tm1, comb);
  hipLaunchKernelGGL(k_gemm2_8ph, dim3(512), dim3(512), 0, stream,
                     comb, Wlb, bl, c, out);
}

// Round 5
// 234.365 us; speedup vs baseline: 1.1067x; 1.0368x over previous
//
#include <hip/hip_runtime.h>
#include <hip/hip_bf16.h>
#include <math.h>

// ---------- types ----------
typedef __bf16 bf16x8 __attribute__((ext_vector_type(8)));
typedef float  f32x4  __attribute__((ext_vector_type(4)));

#define B_ROWS 8192
#define HSZ    1024

// async global->LDS, 16B per lane. LDS dest must be wave-uniform-base + lane*16.
#define GLOAD16(gsrc, ldst)                                                          \
  __builtin_amdgcn_global_load_lds((const __attribute__((address_space(1))) void*)(gsrc), \
                                   (__attribute__((address_space(3))) void*)(ldst),  \
                                   16, 0, 0)

__device__ inline unsigned short f2bf(float f) {
  union { float f; unsigned u; } x; x.f = f;
  unsigned r = x.u + 0x7fffu + ((x.u >> 16) & 1u);   // RNE
  return (unsigned short)(r >> 16);
}

__device__ inline void store4bf(unsigned short* p, float4 v) {
  ushort4 u;
  u.x = f2bf(v.x); u.y = f2bf(v.y); u.z = f2bf(v.z); u.w = f2bf(v.w);
  *(ushort4*)p = u;  // 8B store
}

__device__ inline float sigm(float x) { return 1.0f / (1.0f + __expf(-x)); }

// ---------- kernel 0: fp32 -> bf16 conversion + T precompute ----------
__global__ void k_convert(const float* __restrict__ inp,   // [8192][1025]
                          const float* __restrict__ h,     // [8192][1024]
                          const float* __restrict__ Wl,    // [4096][2048]
                          const float* __restrict__ Wd,    // [1024][1024]
                          unsigned short* __restrict__ comb, // [8192][2048] bf16 bits (cols 0..1023 = x)
                          unsigned short* __restrict__ Wlb,  // [4096][2048]
                          unsigned short* __restrict__ hb,   // [8192][1024]
                          unsigned short* __restrict__ Wdb,  // [1024][1024]
                          float* __restrict__ Tm1) {         // [8192] = T-1
  const long stride = (long)gridDim.x * blockDim.x;
  const long tid0 = (long)blockIdx.x * blockDim.x + threadIdx.x;

  for (long i = tid0; i < (long)B_ROWS * HSZ / 4; i += stride) {
    float4 v = ((const float4*)h)[i];
    store4bf(hb + i * 4, v);
  }
  for (long i = tid0; i < (long)B_ROWS * HSZ / 4; i += stride) {
    long e = i * 4; long b = e >> 10; long c = e & 1023;
    float4 v = *(const float4*)(inp + b * 1025 + c);
    store4bf(comb + b * 2048 + c, v);
  }
  for (long i = tid0; i < 4096L * 2048 / 4; i += stride) {
    float4 v = ((const float4*)Wl)[i];
    store4bf(Wlb + i * 4, v);
  }
  for (long i = tid0; i < 1024L * 1024 / 4; i += stride) {
    float4 v = ((const float4*)Wd)[i];
    store4bf(Wdb + i * 4, v);
  }
  for (long i = tid0; i < B_ROWS; i += stride) {
    float dt = inp[i * 1025 + 1024];
    Tm1[i] = 1.0f / logf(dt + 2.7183f) - 1.0f;
  }
}

// ---------- kernel 1: C_ST GEMM (8192x1024x1024) + h_adj epilogue (known-good) ----------
__global__ void k_gemm1(const unsigned short* __restrict__ A,   // hb  [8192][1024]
                        const unsigned short* __restrict__ Bm,  // Wdb [1024][1024]
                        const float* __restrict__ h,            // h_cur f32
                        const float* __restrict__ bd,           // b_desc [1024]
                        const float* __restrict__ Tm1,
                        unsigned short* __restrict__ comb) {
  const int K = 1024;
  __shared__ __align__(16) unsigned short As[128 * 32];
  __shared__ __align__(16) unsigned short Bs[128 * 32];
  const int tid = threadIdx.x;
  const int lane = tid & 63;
  const int wave = tid >> 6;
  const int wr = wave >> 1, wc = wave & 1;
  const int bRow = blockIdx.x;    // 0..63
  const int bCol = blockIdx.y;    // 0..7

  const int sRow = tid >> 2;
  const int sK = (tid & 3) * 8;
  const unsigned short* aSrc0 = A + (long)(bRow * 128 + sRow) * K + sK;
  const unsigned short* aSrc1 = A + (long)(bRow * 128 + 64 + sRow) * K + sK;
  const unsigned short* bSrc0 = Bm + (long)(bCol * 128 + sRow) * K + sK;
  const unsigned short* bSrc1 = Bm + (long)(bCol * 128 + 64 + sRow) * K + sK;
  unsigned short* aDst0 = As + tid * 8;
  unsigned short* aDst1 = As + 2048 + tid * 8;
  unsigned short* bDst0 = Bs + tid * 8;
  unsigned short* bDst1 = Bs + 2048 + tid * 8;

  f32x4 acc[4][4] = {};
  const int fr = lane & 15, fk = (lane >> 4) * 8;

  for (int k0 = 0; k0 < K; k0 += 32) {
    GLOAD16(aSrc0 + k0, aDst0);
    GLOAD16(aSrc1 + k0, aDst1);
    GLOAD16(bSrc0 + k0, bDst0);
    GLOAD16(bSrc1 + k0, bDst1);
    __syncthreads();
    bf16x8 a[4], b[4];
#pragma unroll
    for (int m = 0; m < 4; m++) a[m] = *(const bf16x8*)(As + (wr * 64 + m * 16 + fr) * 32 + fk);
#pragma unroll
    for (int n = 0; n < 4; n++) b[n] = *(const bf16x8*)(Bs + (wc * 64 + n * 16 + fr) * 32 + fk);
#pragma unroll
    for (int m = 0; m < 4; m++)
#pragma unroll
      for (int n = 0; n < 4; n++)
        acc[m][n] = __builtin_amdgcn_mfma_f32_16x16x32_bf16(a[m], b[n], acc[m][n], 0, 0, 0);
    __syncthreads();
  }

  const int cr = (lane >> 4) * 4;
  const int cc = lane & 15;
#pragma unroll
  for (int m = 0; m < 4; m++)
#pragma unroll
    for (int n = 0; n < 4; n++) {
      const int col = bCol * 128 + wc * 64 + n * 16 + cc;
#pragma unroll
      for (int r = 0; r < 4; r++) {
        const int row = bRow * 128 + wr * 64 + m * 16 + cr + r;
        float v = acc[m][n][r] + bd[col];
        float cst = tanhf(v);
        float hadj = h[(long)row * HSZ + col] + Tm1[row] * cst;
        comb[(long)row * 2048 + 1024 + col] = f2bf(hadj);
      }
    }
}

// ---------- kernel 2: gates GEMM, 256x256 tile, ring-4 LDS, cross-phase pipelined ----------
// ds_reads issued one phase ahead of consuming MFMA; 1 barrier per K-tile (publish point
// mid-tile); counted vmcnt(6); MFMA-B cluster runs waitless over next-tile reads + staging.
#define NT2 64   // 2048/32
__global__ __launch_bounds__(512, 2)
void k_gemm2_pipe(const unsigned short* __restrict__ A,   // comb [8192][2048]
                  const unsigned short* __restrict__ Bm,  // Wlb  [4096][2048]
                  const float* __restrict__ bl,           // b_layers [4096]
                  const float* __restrict__ c_cur,        // f32 [8192][1024]
                  float* __restrict__ out) {              // h_next | c_next (f32)
  // ring[4] buffers: each 32KB = A-tile [256][32] (16KB) | B-tile [256][32] (16KB)
  __shared__ __align__(16) unsigned short lds[4][16384];

  const int tid = threadIdx.x;
  const int lane = tid & 63;
  const int wid = tid >> 6;
  const int wr = wid >> 2;          // 0..1 : row half (128 rows)
  const int wc = wid & 3;           // 0..3 : col quarter (64 local cols = 16 j x 4 gates)

  // XCD-bijective block swizzle (512 blocks, 512%8==0)
  const int bid = blockIdx.x;
  const int swz = (bid & 7) * 64 + (bid >> 3);
  const int bRow = swz & 31;        // 0..31
  const int bCol = swz >> 5;        // 0..15

  // ---- staging addresses (pre-swizzled global source; LDS dest linear) ----
  const int sr = tid >> 2;                 // 0..127
  const int swsel = (sr >> 1) & 3;
  const int gk = ((tid & 3) ^ swsel) << 3;
  const unsigned short* aBase = A + (long)(bRow * 256 + sr) * 2048 + gk;
  const int rl0 = sr, rl1 = 128 + sr;
  const int grow0 = ((rl0 >> 4) & 3) * 1024 + bCol * 64 + (rl0 >> 6) * 16 + (rl0 & 15);
  const int grow1 = ((rl1 >> 4) & 3) * 1024 + bCol * 64 + (rl1 >> 6) * 16 + (rl1 & 15);
  const unsigned short* bBase0 = Bm + (long)grow0 * 2048 + gk;
  const unsigned short* bBase1 = Bm + (long)grow1 * 2048 + gk;

#define STAGE_A2(tt) { unsigned short* d_ = &lds[(tt) & 3][0] + tid * 8;          \
    GLOAD16(aBase + (long)(tt) * 32, d_);                                          \
    GLOAD16(aBase + 128L * 2048 + (long)(tt) * 32, d_ + 512 * 8); }
#define STAGE_B2(tt) { unsigned short* d_ = &lds[(tt) & 3][8192] + tid * 8;       \
    GLOAD16(bBase0 + (long)(tt) * 32, d_);                                         \
    GLOAD16(bBase1 + (long)(tt) * 32, d_ + 512 * 8); }

  // ---- fragment read offsets (swizzled), in ushort units ----
  const int fr = lane & 15, q = lane >> 4;
  int offA[8], offB[4];
#pragma unroll
  for (int m = 0; m < 8; m++) {
    const int row = wr * 128 + m * 16 + fr;
    offA[m] = row * 32 + ((q ^ ((row >> 1) & 3)) << 3);
  }
#pragma unroll
  for (int n = 0; n < 4; n++) {
    const int row = wc * 64 + n * 16 + fr;
    offB[n] = 8192 + row * 32 + ((q ^ ((row >> 1) & 3)) << 3);
  }

  f32x4 acc[8][4] = {};   // [m][gate]
  bf16x8 aL0[4], aL1[4], b0[4], b1[4], aH[4];

  // ---- prologue: stage tiles 0,1,2; publish tile 0; read tile-0 phase-A frags ----
  STAGE_A2(0); STAGE_B2(0);
  STAGE_A2(1); STAGE_B2(1);
  STAGE_A2(2); STAGE_B2(2);
  asm volatile("s_waitcnt vmcnt(8)" ::: "memory");   // oldest 4 = tile 0 A+B landed
  __builtin_amdgcn_sched_barrier(0);
  __builtin_amdgcn_s_barrier();
  __builtin_amdgcn_sched_barrier(0);
#pragma unroll
  for (int m = 0; m < 4; m++) aL0[m] = *(const bf16x8*)(&lds[0][0] + offA[m]);
#pragma unroll
  for (int n = 0; n < 4; n++) b0[n] = *(const bf16x8*)(&lds[0][0] + offB[n]);

  // TILE_BODY(t, aC, bC, aN, bN):
  //  phase A: issue aH(t) reads + STAGE_A2(t+3); MFMA m0-3 on (aC,bC);
  //           lgkmcnt(0); vmcnt(publish t+1); barrier
  //  phase B: issue aN/bN reads (tile t+1) + STAGE_B2(t+3); MFMA m4-7 on (aH,bC) waitless
#define TILE_BODY(t, aC, bC, aN, bN)                                                 \
  {                                                                                  \
    const unsigned short* buf = lds[(t) & 3];                                        \
    _Pragma("unroll")                                                                \
    for (int m = 0; m < 4; m++) aH[m] = *(const bf16x8*)(buf + offA[m + 4]);         \
    if ((t) < NT2 - 3) STAGE_A2((t) + 3);                                            \
    __builtin_amdgcn_sched_barrier(0);                                               \
    __builtin_amdgcn_s_setprio(1);                                                   \
    _Pragma("unroll")                                                                \
    for (int m = 0; m < 4; m++)                                                      \
      _Pragma("unroll")                                                              \
      for (int n = 0; n < 4; n++)                                                    \
        acc[m][n] = __builtin_amdgcn_mfma_f32_16x16x32_bf16(aC[m], bC[n], acc[m][n], 0, 0, 0); \
    __builtin_amdgcn_s_setprio(0);                                                   \
    asm volatile("s_waitcnt lgkmcnt(0)" ::: "memory");                               \
    if ((t) < NT2 - 3)        { asm volatile("s_waitcnt vmcnt(6)" ::: "memory"); }   \
    else if ((t) == NT2 - 3)  { asm volatile("s_waitcnt vmcnt(4)" ::: "memory"); }   \
    else                      { asm volatile("s_waitcnt vmcnt(0)" ::: "memory"); }   \
    __builtin_amdgcn_sched_barrier(0);                                               \
    __builtin_amdgcn_s_barrier();                                                    \
    __builtin_amdgcn_sched_barrier(0);                                               \
    if ((t) < NT2 - 1) {                                                             \
      const unsigned short* bufN = lds[((t) + 1) & 3];                               \
      _Pragma("unroll")                                                              \
      for (int m = 0; m < 4; m++) aN[m] = *(const bf16x8*)(bufN + offA[m]);          \
      _Pragma("unroll")                                                              \
      for (int n = 0; n < 4; n++) bN[n] = *(const bf16x8*)(bufN + offB[n]);          \
      if ((t) < NT2 - 3) STAGE_B2((t) + 3);                                          \
    }                                                                                \
    __builtin_amdgcn_sched_barrier(0);                                               \
    __builtin_amdgcn_s_setprio(1);                                                   \
    _Pragma("unroll")                                                                \
    for (int m = 0; m < 4; m++)                                                      \
      _Pragma("unroll")                                                              \
      for (int n = 0; n < 4; n++)                                                    \
        acc[m + 4][n] = __builtin_amdgcn_mfma_f32_16x16x32_bf16(aH[m], bC[n], acc[m + 4][n], 0, 0, 0); \
    __builtin_amdgcn_s_setprio(0);                                                   \
  }

  for (int t = 0; t < NT2; t += 2) {
    TILE_BODY(t,     aL0, b0, aL1, b1);
    TILE_BODY(t + 1, aL1, b1, aL0, b0);
  }
#undef TILE_BODY

  // ---- fused LSTM epilogue ----
  const int cr = (lane >> 4) * 4;
  const int cc = lane & 15;
  const int j = bCol * 64 + wc * 16 + cc;       // 0..1023
#pragma unroll
  for (int m = 0; m < 8; m++) {
#pragma unroll
    for (int r = 0; r < 4; r++) {
      const int row = bRow * 256 + wr * 128 + m * 16 + cr + r;
      float iv = sigm(acc[m][0][r] + bl[j]);
      float fv = sigm(acc[m][1][r] + bl[1024 + j]);
      float ov = sigm(acc[m][2][r] + bl[2048 + j]);
      float gv = tanhf(acc[m][3][r] + bl[3072 + j]);
      float cn = fv * c_cur[(long)row * HSZ + j] + iv * gv;
      float hn = ov * tanhf(cn);
      out[(long)row * HSZ + j] = hn;                         // h_next
      out[(long)B_ROWS * HSZ + (long)row * HSZ + j] = cn;    // c_next
    }
  }
}

// ---------- launch ----------
extern "C" void kernel_launch(void* const* d_in, const int* in_sizes, int n_in,
                              void* d_out, int out_size, void* d_ws, size_t ws_size,
                              hipStream_t stream) {
  const float* inp = (const float*)d_in[0];   // input_tensor [8192][1025]
  const float* h   = (const float*)d_in[1];   // h_cur
  const float* c   = (const float*)d_in[2];   // c_cur
  const float* Wl  = (const float*)d_in[3];   // W_layers [4096][2048]
  const float* bl  = (const float*)d_in[4];   // b_layers [4096]
  const float* Wd  = (const float*)d_in[5];   // W_desc [1024][1024]
  const float* bd  = (const float*)d_in[6];   // b_desc [1024]

  char* ws = (char*)d_ws;
  unsigned short* comb = (unsigned short*)(ws);               // 33,554,432 B
  unsigned short* Wlb  = (unsigned short*)(ws + 33554432);    // 16,777,216 B
  unsigned short* hb   = (unsigned short*)(ws + 50331648);    // 16,777,216 B
  unsigned short* Wdb  = (unsigned short*)(ws + 67108864);    //  2,097,152 B
  float*          Tm1  = (float*)(ws + 69206016);             //     32,768 B
  float*          out  = (float*)d_out;                       // f32 outputs

  hipLaunchKernelGGL(k_convert, dim3(2048), dim3(256), 0, stream,
                     inp, h, Wl, Wd, comb, Wlb, hb, Wdb, Tm1);
  hipLaunchKernelGGL(k_gemm1, dim3(64, 8), dim3(256), 0, stream,
                     hb, Wdb, h, bd, Tm1, comb);
  hipLaunchKernelGGL(k_gemm2_pipe, dim3(512), dim3(512), 0, stream,
                     comb, Wlb, bl, c, out);
}

// Round 6
// 227.403 us; speedup vs baseline: 1.1406x; 1.0306x over previous
//
#include <hip/hip_runtime.h>
#include <hip/hip_bf16.h>
#include <math.h>

// ---------- types ----------
typedef __bf16 bf16x8 __attribute__((ext_vector_type(8)));
typedef float  f32x4  __attribute__((ext_vector_type(4)));

#define B_ROWS 8192
#define HSZ    1024

// async global->LDS, 16B per lane. LDS dest must be wave-uniform-base + lane*16.
#define GLOAD16(gsrc, ldst)                                                          \
  __builtin_amdgcn_global_load_lds((const __attribute__((address_space(1))) void*)(gsrc), \
                                   (__attribute__((address_space(3))) void*)(ldst),  \
                                   16, 0, 0)

__device__ inline unsigned short f2bf(float f) {
  union { float f; unsigned u; } x; x.f = f;
  unsigned r = x.u + 0x7fffu + ((x.u >> 16) & 1u);   // RNE
  return (unsigned short)(r >> 16);
}

__device__ inline void store4bf(unsigned short* p, float4 v) {
  ushort4 u;
  u.x = f2bf(v.x); u.y = f2bf(v.y); u.z = f2bf(v.z); u.w = f2bf(v.w);
  *(ushort4*)p = u;  // 8B store
}

__device__ inline float sigm(float x) { return 1.0f / (1.0f + __expf(-x)); }

// ---------- kernel 0: fp32 -> bf16 conversion + T precompute ----------
__global__ void k_convert(const float* __restrict__ inp,   // [8192][1025]
                          const float* __restrict__ h,     // [8192][1024]
                          const float* __restrict__ Wl,    // [4096][2048]
                          const float* __restrict__ Wd,    // [1024][1024]
                          unsigned short* __restrict__ comb, // [8192][2048] bf16 bits (cols 0..1023 = x)
                          unsigned short* __restrict__ Wlb,  // [4096][2048]
                          unsigned short* __restrict__ hb,   // [8192][1024]
                          unsigned short* __restrict__ Wdb,  // [1024][1024]
                          float* __restrict__ Tm1) {         // [8192] = T-1
  const long stride = (long)gridDim.x * blockDim.x;
  const long tid0 = (long)blockIdx.x * blockDim.x + threadIdx.x;

  for (long i = tid0; i < (long)B_ROWS * HSZ / 4; i += stride) {
    float4 v = ((const float4*)h)[i];
    store4bf(hb + i * 4, v);
  }
  for (long i = tid0; i < (long)B_ROWS * HSZ / 4; i += stride) {
    long e = i * 4; long b = e >> 10; long c = e & 1023;
    float4 v = *(const float4*)(inp + b * 1025 + c);
    store4bf(comb + b * 2048 + c, v);
  }
  for (long i = tid0; i < 4096L * 2048 / 4; i += stride) {
    float4 v = ((const float4*)Wl)[i];
    store4bf(Wlb + i * 4, v);
  }
  for (long i = tid0; i < 1024L * 1024 / 4; i += stride) {
    float4 v = ((const float4*)Wd)[i];
    store4bf(Wdb + i * 4, v);
  }
  for (long i = tid0; i < B_ROWS; i += stride) {
    float dt = inp[i * 1025 + 1024];
    Tm1[i] = 1.0f / logf(dt + 2.7183f) - 1.0f;
  }
}

// ---------- kernel 1: C_ST GEMM (8192x1024x1024) + h_adj epilogue (known-good) ----------
__global__ void k_gemm1(const unsigned short* __restrict__ A,   // hb  [8192][1024]
                        const unsigned short* __restrict__ Bm,  // Wdb [1024][1024]
                        const float* __restrict__ h,            // h_cur f32
                        const float* __restrict__ bd,           // b_desc [1024]
                        const float* __restrict__ Tm1,
                        unsigned short* __restrict__ comb) {
  const int K = 1024;
  __shared__ __align__(16) unsigned short As[128 * 32];
  __shared__ __align__(16) unsigned short Bs[128 * 32];
  const int tid = threadIdx.x;
  const int lane = tid & 63;
  const int wave = tid >> 6;
  const int wr = wave >> 1, wc = wave & 1;
  const int bRow = blockIdx.x;    // 0..63
  const int bCol = blockIdx.y;    // 0..7

  const int sRow = tid >> 2;
  const int sK = (tid & 3) * 8;
  const unsigned short* aSrc0 = A + (long)(bRow * 128 + sRow) * K + sK;
  const unsigned short* aSrc1 = A + (long)(bRow * 128 + 64 + sRow) * K + sK;
  const unsigned short* bSrc0 = Bm + (long)(bCol * 128 + sRow) * K + sK;
  const unsigned short* bSrc1 = Bm + (long)(bCol * 128 + 64 + sRow) * K + sK;
  unsigned short* aDst0 = As + tid * 8;
  unsigned short* aDst1 = As + 2048 + tid * 8;
  unsigned short* bDst0 = Bs + tid * 8;
  unsigned short* bDst1 = Bs + 2048 + tid * 8;

  f32x4 acc[4][4] = {};
  const int fr = lane & 15, fk = (lane >> 4) * 8;

  for (int k0 = 0; k0 < K; k0 += 32) {
    GLOAD16(aSrc0 + k0, aDst0);
    GLOAD16(aSrc1 + k0, aDst1);
    GLOAD16(bSrc0 + k0, bDst0);
    GLOAD16(bSrc1 + k0, bDst1);
    __syncthreads();
    bf16x8 a[4], b[4];
#pragma unroll
    for (int m = 0; m < 4; m++) a[m] = *(const bf16x8*)(As + (wr * 64 + m * 16 + fr) * 32 + fk);
#pragma unroll
    for (int n = 0; n < 4; n++) b[n] = *(const bf16x8*)(Bs + (wc * 64 + n * 16 + fr) * 32 + fk);
#pragma unroll
    for (int m = 0; m < 4; m++)
#pragma unroll
      for (int n = 0; n < 4; n++)
        acc[m][n] = __builtin_amdgcn_mfma_f32_16x16x32_bf16(a[m], b[n], acc[m][n], 0, 0, 0);
    __syncthreads();
  }

  const int cr = (lane >> 4) * 4;
  const int cc = lane & 15;
#pragma unroll
  for (int m = 0; m < 4; m++)
#pragma unroll
    for (int n = 0; n < 4; n++) {
      const int col = bCol * 128 + wc * 64 + n * 16 + cc;
#pragma unroll
      for (int r = 0; r < 4; r++) {
        const int row = bRow * 128 + wr * 64 + m * 16 + cr + r;
        float v = acc[m][n][r] + bd[col];
        float cst = tanhf(v);
        float hadj = h[(long)row * HSZ + col] + Tm1[row] * cst;
        comb[(long)row * 2048 + 1024 + col] = f2bf(hadj);
      }
    }
}

// ---------- kernel 2: gates GEMM, 256x256 tile, ring-4 LDS, cross-phase pipelined ----------
// R6 change (single variable): L2-aware XCD mapping. Each XCD owns bRow in
// [4*xcd, 4*xcd+4) x all 16 bCols, ordered as 2-bRow x 16-bCol sweeps so the
// A K-step stays L2-resident (read by 16 co-resident blocks) and B-panels are
// shared by adjacent-bid pairs. Cuts L3->XCD traffic ~120MB -> ~36MB per XCD.
#define NT2 64   // 2048/32
__global__ __launch_bounds__(512, 2)
void k_gemm2_pipe(const unsigned short* __restrict__ A,   // comb [8192][2048]
                  const unsigned short* __restrict__ Bm,  // Wlb  [4096][2048]
                  const float* __restrict__ bl,           // b_layers [4096]
                  const float* __restrict__ c_cur,        // f32 [8192][1024]
                  float* __restrict__ out) {              // h_next | c_next (f32)
  // ring[4] buffers: each 32KB = A-tile [256][32] (16KB) | B-tile [256][32] (16KB)
  __shared__ __align__(16) unsigned short lds[4][16384];

  const int tid = threadIdx.x;
  const int lane = tid & 63;
  const int wid = tid >> 6;
  const int wr = wid >> 2;          // 0..1 : row half (128 rows)
  const int wc = wid & 3;           // 0..3 : col quarter (64 local cols = 16 j x 4 gates)

  // L2-aware XCD mapping (bijective over 512 blocks; dispatch round-robins bid%8)
  const int bid = blockIdx.x;
  const int xcd = bid & 7;
  const int ii = bid >> 3;          // 0..63 within-XCD
  const int sweep = ii >> 5;        // 0..1
  const int pos = ii & 31;          // 0..31
  const int bRow = xcd * 4 + sweep * 2 + (pos & 1);   // 0..31
  const int bCol = pos >> 1;                          // 0..15

  // ---- staging addresses (pre-swizzled global source; LDS dest linear) ----
  const int sr = tid >> 2;                 // 0..127
  const int swsel = (sr >> 1) & 3;
  const int gk = ((tid & 3) ^ swsel) << 3;
  const unsigned short* aBase = A + (long)(bRow * 256 + sr) * 2048 + gk;
  const int rl0 = sr, rl1 = 128 + sr;
  const int grow0 = ((rl0 >> 4) & 3) * 1024 + bCol * 64 + (rl0 >> 6) * 16 + (rl0 & 15);
  const int grow1 = ((rl1 >> 4) & 3) * 1024 + bCol * 64 + (rl1 >> 6) * 16 + (rl1 & 15);
  const unsigned short* bBase0 = Bm + (long)grow0 * 2048 + gk;
  const unsigned short* bBase1 = Bm + (long)grow1 * 2048 + gk;

#define STAGE_A2(tt) { unsigned short* d_ = &lds[(tt) & 3][0] + tid * 8;          \
    GLOAD16(aBase + (long)(tt) * 32, d_);                                          \
    GLOAD16(aBase + 128L * 2048 + (long)(tt) * 32, d_ + 512 * 8); }
#define STAGE_B2(tt) { unsigned short* d_ = &lds[(tt) & 3][8192] + tid * 8;       \
    GLOAD16(bBase0 + (long)(tt) * 32, d_);                                         \
    GLOAD16(bBase1 + (long)(tt) * 32, d_ + 512 * 8); }

  // ---- fragment read offsets (swizzled), in ushort units ----
  const int fr = lane & 15, q = lane >> 4;
  int offA[8], offB[4];
#pragma unroll
  for (int m = 0; m < 8; m++) {
    const int row = wr * 128 + m * 16 + fr;
    offA[m] = row * 32 + ((q ^ ((row >> 1) & 3)) << 3);
  }
#pragma unroll
  for (int n = 0; n < 4; n++) {
    const int row = wc * 64 + n * 16 + fr;
    offB[n] = 8192 + row * 32 + ((q ^ ((row >> 1) & 3)) << 3);
  }

  f32x4 acc[8][4] = {};   // [m][gate]
  bf16x8 aL0[4], aL1[4], b0[4], b1[4], aH[4];

  // ---- prologue: stage tiles 0,1,2; publish tile 0; read tile-0 phase-A frags ----
  STAGE_A2(0); STAGE_B2(0);
  STAGE_A2(1); STAGE_B2(1);
  STAGE_A2(2); STAGE_B2(2);
  asm volatile("s_waitcnt vmcnt(8)" ::: "memory");   // oldest 4 = tile 0 A+B landed
  __builtin_amdgcn_sched_barrier(0);
  __builtin_amdgcn_s_barrier();
  __builtin_amdgcn_sched_barrier(0);
#pragma unroll
  for (int m = 0; m < 4; m++) aL0[m] = *(const bf16x8*)(&lds[0][0] + offA[m]);
#pragma unroll
  for (int n = 0; n < 4; n++) b0[n] = *(const bf16x8*)(&lds[0][0] + offB[n]);

  // TILE_BODY(t, aC, bC, aN, bN):
  //  phase A: issue aH(t) reads + STAGE_A2(t+3); MFMA m0-3 on (aC,bC);
  //           lgkmcnt(0); vmcnt(publish t+1); barrier
  //  phase B: issue aN/bN reads (tile t+1) + STAGE_B2(t+3); MFMA m4-7 on (aH,bC) waitless
#define TILE_BODY(t, aC, bC, aN, bN)                                                 \
  {                                                                                  \
    const unsigned short* buf = lds[(t) & 3];                                        \
    _Pragma("unroll")                                                                \
    for (int m = 0; m < 4; m++) aH[m] = *(const bf16x8*)(buf + offA[m + 4]);         \
    if ((t) < NT2 - 3) STAGE_A2((t) + 3);                                            \
    __builtin_amdgcn_sched_barrier(0);                                               \
    __builtin_amdgcn_s_setprio(1);                                                   \
    _Pragma("unroll")                                                                \
    for (int m = 0; m < 4; m++)                                                      \
      _Pragma("unroll")                                                              \
      for (int n = 0; n < 4; n++)                                                    \
        acc[m][n] = __builtin_amdgcn_mfma_f32_16x16x32_bf16(aC[m], bC[n], acc[m][n], 0, 0, 0); \
    __builtin_amdgcn_s_setprio(0);                                                   \
    asm volatile("s_waitcnt lgkmcnt(0)" ::: "memory");                               \
    if ((t) < NT2 - 3)        { asm volatile("s_waitcnt vmcnt(6)" ::: "memory"); }   \
    else if ((t) == NT2 - 3)  { asm volatile("s_waitcnt vmcnt(4)" ::: "memory"); }   \
    else                      { asm volatile("s_waitcnt vmcnt(0)" ::: "memory"); }   \
    __builtin_amdgcn_sched_barrier(0);                                               \
    __builtin_amdgcn_s_barrier();                                                    \
    __builtin_amdgcn_sched_barrier(0);                                               \
    if ((t) < NT2 - 1) {                                                             \
      const unsigned short* bufN = lds[((t) + 1) & 3];                               \
      _Pragma("unroll")                                                              \
      for (int m = 0; m < 4; m++) aN[m] = *(const bf16x8*)(bufN + offA[m]);          \
      _Pragma("unroll")                                                              \
      for (int n = 0; n < 4; n++) bN[n] = *(const bf16x8*)(bufN + offB[n]);          \
      if ((t) < NT2 - 3) STAGE_B2((t) + 3);                                          \
    }                                                                                \
    __builtin_amdgcn_sched_barrier(0);                                               \
    __builtin_amdgcn_s_setprio(1);                                                   \
    _Pragma("unroll")                                                                \
    for (int m = 0; m < 4; m++)                                                      \
      _Pragma("unroll")                                                              \
      for (int n = 0; n < 4; n++)                                                    \
        acc[m + 4][n] = __builtin_amdgcn_mfma_f32_16x16x32_bf16(aH[m], bC[n], acc[m + 4][n], 0, 0, 0); \
    __builtin_amdgcn_s_setprio(0);                                                   \
  }

  for (int t = 0; t < NT2; t += 2) {
    TILE_BODY(t,     aL0, b0, aL1, b1);
    TILE_BODY(t + 1, aL1, b1, aL0, b0);
  }
#undef TILE_BODY

  // ---- fused LSTM epilogue ----
  const int cr = (lane >> 4) * 4;
  const int cc = lane & 15;
  const int j = bCol * 64 + wc * 16 + cc;       // 0..1023
#pragma unroll
  for (int m = 0; m < 8; m++) {
#pragma unroll
    for (int r = 0; r < 4; r++) {
      const int row = bRow * 256 + wr * 128 + m * 16 + cr + r;
      float iv = sigm(acc[m][0][r] + bl[j]);
      float fv = sigm(acc[m][1][r] + bl[1024 + j]);
      float ov = sigm(acc[m][2][r] + bl[2048 + j]);
      float gv = tanhf(acc[m][3][r] + bl[3072 + j]);
      float cn = fv * c_cur[(long)row * HSZ + j] + iv * gv;
      float hn = ov * tanhf(cn);
      out[(long)row * HSZ + j] = hn;                         // h_next
      out[(long)B_ROWS * HSZ + (long)row * HSZ + j] = cn;    // c_next
    }
  }
}

// ---------- launch ----------
extern "C" void kernel_launch(void* const* d_in, const int* in_sizes, int n_in,
                              void* d_out, int out_size, void* d_ws, size_t ws_size,
                              hipStream_t stream) {
  const float* inp = (const float*)d_in[0];   // input_tensor [8192][1025]
  const float* h   = (const float*)d_in[1];   // h_cur
  const float* c   = (const float*)d_in[2];   // c_cur
  const float* Wl  = (const float*)d_in[3];   // W_layers [4096][2048]
  const float* bl  = (const float*)d_in[4];   // b_layers [4096]
  const float* Wd  = (const float*)d_in[5];   // W_desc [1024][1024]
  const float* bd  = (const float*)d_in[6];   // b_desc [1024]

  char* ws = (char*)d_ws;
  unsigned short* comb = (unsigned short*)(ws);               // 33,554,432 B
  unsigned short* Wlb  = (unsigned short*)(ws + 33554432);    // 16,777,216 B
  unsigned short* hb   = (unsigned short*)(ws + 50331648);    // 16,777,216 B
  unsigned short* Wdb  = (unsigned short*)(ws + 67108864);    //  2,097,152 B
  float*          Tm1  = (float*)(ws + 69206016);             //     32,768 B
  float*          out  = (float*)d_out;                       // f32 outputs

  hipLaunchKernelGGL(k_convert, dim3(2048), dim3(256), 0, stream,
                     inp, h, Wl, Wd, comb, Wlb, hb, Wdb, Tm1);
  hipLaunchKernelGGL(k_gemm1, dim3(64, 8), dim3(256), 0, stream,
                     hb, Wdb, h, bd, Tm1, comb);
  hipLaunchKernelGGL(k_gemm2_pipe, dim3(512), dim3(512), 0, stream,
                     comb, Wlb, bl, c, out);
}

// Round 7
// 226.958 us; speedup vs baseline: 1.1428x; 1.0020x over previous
//
#include <hip/hip_runtime.h>
#include <hip/hip_bf16.h>
#include <math.h>

// ---------- types ----------
typedef __bf16 bf16x8 __attribute__((ext_vector_type(8)));
typedef float  f32x4  __attribute__((ext_vector_type(4)));

#define B_ROWS 8192
#define HSZ    1024

// async global->LDS, 16B per lane. LDS dest must be wave-uniform-base + lane*16.
#define GLOAD16(gsrc, ldst)                                                          \
  __builtin_amdgcn_global_load_lds((const __attribute__((address_space(1))) void*)(gsrc), \
                                   (__attribute__((address_space(3))) void*)(ldst),  \
                                   16, 0, 0)

__device__ inline unsigned short f2bf(float f) {
  union { float f; unsigned u; } x; x.f = f;
  unsigned r = x.u + 0x7fffu + ((x.u >> 16) & 1u);   // RNE
  return (unsigned short)(r >> 16);
}

__device__ inline void store4bf(unsigned short* p, float4 v) {
  ushort4 u;
  u.x = f2bf(v.x); u.y = f2bf(v.y); u.z = f2bf(v.z); u.w = f2bf(v.w);
  *(ushort4*)p = u;  // 8B store
}

__device__ inline float sigm(float x) { return 1.0f / (1.0f + __expf(-x)); }

// ---------- kernel 0: fp32 -> bf16 conversion + T precompute ----------
__global__ void k_convert(const float* __restrict__ inp,   // [8192][1025]
                          const float* __restrict__ h,     // [8192][1024]
                          const float* __restrict__ Wl,    // [4096][2048]
                          const float* __restrict__ Wd,    // [1024][1024]
                          unsigned short* __restrict__ comb, // [8192][2048] bf16 bits (cols 0..1023 = x)
                          unsigned short* __restrict__ Wlb,  // [4096][2048]
                          unsigned short* __restrict__ hb,   // [8192][1024]
                          unsigned short* __restrict__ Wdb,  // [1024][1024]
                          float* __restrict__ Tm1) {         // [8192] = T-1
  const long stride = (long)gridDim.x * blockDim.x;
  const long tid0 = (long)blockIdx.x * blockDim.x + threadIdx.x;

  for (long i = tid0; i < (long)B_ROWS * HSZ / 4; i += stride) {
    float4 v = ((const float4*)h)[i];
    store4bf(hb + i * 4, v);
  }
  for (long i = tid0; i < (long)B_ROWS * HSZ / 4; i += stride) {
    long e = i * 4; long b = e >> 10; long c = e & 1023;
    float4 v = *(const float4*)(inp + b * 1025 + c);
    store4bf(comb + b * 2048 + c, v);
  }
  for (long i = tid0; i < 4096L * 2048 / 4; i += stride) {
    float4 v = ((const float4*)Wl)[i];
    store4bf(Wlb + i * 4, v);
  }
  for (long i = tid0; i < 1024L * 1024 / 4; i += stride) {
    float4 v = ((const float4*)Wd)[i];
    store4bf(Wdb + i * 4, v);
  }
  for (long i = tid0; i < B_ROWS; i += stride) {
    float dt = inp[i * 1025 + 1024];
    Tm1[i] = 1.0f / logf(dt + 2.7183f) - 1.0f;
  }
}

// ---------- kernel 1: C_ST GEMM (8192x1024x1024) + h_adj epilogue (known-good) ----------
__global__ void k_gemm1(const unsigned short* __restrict__ A,   // hb  [8192][1024]
                        const unsigned short* __restrict__ Bm,  // Wdb [1024][1024]
                        const float* __restrict__ h,            // h_cur f32
                        const float* __restrict__ bd,           // b_desc [1024]
                        const float* __restrict__ Tm1,
                        unsigned short* __restrict__ comb) {
  const int K = 1024;
  __shared__ __align__(16) unsigned short As[128 * 32];
  __shared__ __align__(16) unsigned short Bs[128 * 32];
  const int tid = threadIdx.x;
  const int lane = tid & 63;
  const int wave = tid >> 6;
  const int wr = wave >> 1, wc = wave & 1;
  const int bRow = blockIdx.x;    // 0..63
  const int bCol = blockIdx.y;    // 0..7

  const int sRow = tid >> 2;
  const int sK = (tid & 3) * 8;
  const unsigned short* aSrc0 = A + (long)(bRow * 128 + sRow) * K + sK;
  const unsigned short* aSrc1 = A + (long)(bRow * 128 + 64 + sRow) * K + sK;
  const unsigned short* bSrc0 = Bm + (long)(bCol * 128 + sRow) * K + sK;
  const unsigned short* bSrc1 = Bm + (long)(bCol * 128 + 64 + sRow) * K + sK;
  unsigned short* aDst0 = As + tid * 8;
  unsigned short* aDst1 = As + 2048 + tid * 8;
  unsigned short* bDst0 = Bs + tid * 8;
  unsigned short* bDst1 = Bs + 2048 + tid * 8;

  f32x4 acc[4][4] = {};
  const int fr = lane & 15, fk = (lane >> 4) * 8;

  for (int k0 = 0; k0 < K; k0 += 32) {
    GLOAD16(aSrc0 + k0, aDst0);
    GLOAD16(aSrc1 + k0, aDst1);
    GLOAD16(bSrc0 + k0, bDst0);
    GLOAD16(bSrc1 + k0, bDst1);
    __syncthreads();
    bf16x8 a[4], b[4];
#pragma unroll
    for (int m = 0; m < 4; m++) a[m] = *(const bf16x8*)(As + (wr * 64 + m * 16 + fr) * 32 + fk);
#pragma unroll
    for (int n = 0; n < 4; n++) b[n] = *(const bf16x8*)(Bs + (wc * 64 + n * 16 + fr) * 32 + fk);
#pragma unroll
    for (int m = 0; m < 4; m++)
#pragma unroll
      for (int n = 0; n < 4; n++)
        acc[m][n] = __builtin_amdgcn_mfma_f32_16x16x32_bf16(a[m], b[n], acc[m][n], 0, 0, 0);
    __syncthreads();
  }

  const int cr = (lane >> 4) * 4;
  const int cc = lane & 15;
#pragma unroll
  for (int m = 0; m < 4; m++)
#pragma unroll
    for (int n = 0; n < 4; n++) {
      const int col = bCol * 128 + wc * 64 + n * 16 + cc;
#pragma unroll
      for (int r = 0; r < 4; r++) {
        const int row = bRow * 128 + wr * 64 + m * 16 + cr + r;
        float v = acc[m][n][r] + bd[col];
        float cst = tanhf(v);
        float hadj = h[(long)row * HSZ + col] + Tm1[row] * cst;
        comb[(long)row * 2048 + 1024 + col] = f2bf(hadj);
      }
    }
}

// ---------- kernel 2: gates GEMM — faithful m201 quadrant-phase template ----------
// BM=BN=256, BK=64, 2 dbufs (2x64KB LDS), 8 waves (2Mx4N), per-wave out 128x64.
// Per K-tile: 4 phases = C-quadrants (mq,nq) order (0,0)(0,1)(1,1)(1,0), frag-cached.
// Each phase: {ds_reads; stage 1 half-tile; barrier; lgkm0; setprio1; 16 MFMA; setprio0; barrier}.
// vmcnt(2) publishes: p3-trail -> A0,A1,B0 of t+1; p0-trail -> B1 of t (vmcnt(0) at last tile).
#define NKT 32   // 2048/64
#define BAR() __builtin_amdgcn_s_barrier()
#define LGKM0() { asm volatile("s_waitcnt lgkmcnt(0)" ::: "memory"); __builtin_amdgcn_sched_barrier(0); }
#define VMW(n) { asm volatile("s_waitcnt vmcnt(" #n ")" ::: "memory"); __builtin_amdgcn_sched_barrier(0); }

__global__ __launch_bounds__(512, 2)
void k_gemm2_q(const unsigned short* __restrict__ A,   // comb [8192][2048]
               const unsigned short* __restrict__ Bm,  // Wlb  [4096][2048]
               const float* __restrict__ bl,           // b_layers [4096]
               const float* __restrict__ c_cur,        // f32 [8192][1024]
               float* __restrict__ out) {              // h_next | c_next (f32)
  // per dbuf 32768 ushorts: [A0 8192][A1 8192][B0 8192][B1 8192]
  __shared__ __align__(16) unsigned short lds2[2][32768];

  const int tid = threadIdx.x;
  const int lane = tid & 63;
  const int wid = tid >> 6;
  const int wr = wid >> 2;          // 0..1 : row half (128 rows)
  const int wc = wid & 3;           // 0..3 : j-col quarter (16 j x 4 gates)

  // L2-aware XCD mapping (kept from R6 — reduced FETCH)
  const int bid = blockIdx.x;
  const int xcd = bid & 7;
  const int ii = bid >> 3;
  const int sweep = ii >> 5;
  const int pos = ii & 31;
  const int bRow = xcd * 4 + sweep * 2 + (pos & 1);   // 0..31
  const int bCol = pos >> 1;                          // 0..15

  // ---- staging: thread stages row strow (of a 64-row gload group), k-slice ssl ----
  const int strow = tid >> 3;                          // 0..63
  const int gkswz = ((tid & 7) ^ (strow & 7)) << 3;    // pre-swizzled k-elem offset
  const unsigned short* aS[4]; const unsigned short* bS[4];   // quarter q4 = h*2+g
#pragma unroll
  for (int q4 = 0; q4 < 4; q4++) {
    aS[q4] = A  + (long)(bRow * 256 + q4 * 64 + strow) * 2048 + gkswz;
    bS[q4] = Bm + (long)(q4 * 1024 + bCol * 64 + strow) * 2048 + gkswz;   // gate q4, j=bCol*64+strow
  }
#define STG_AH(dd, kt, hh) { \
    GLOAD16(aS[(hh)*2 + 0] + (kt)*64, &lds2[dd][(hh)*8192 + 0    + tid*8]); \
    GLOAD16(aS[(hh)*2 + 1] + (kt)*64, &lds2[dd][(hh)*8192 + 4096 + tid*8]); }
#define STG_BH(dd, kt, hh) { \
    GLOAD16(bS[(hh)*2 + 0] + (kt)*64, &lds2[dd][16384 + (hh)*8192 + 0    + tid*8]); \
    GLOAD16(bS[(hh)*2 + 1] + (kt)*64, &lds2[dd][16384 + (hh)*8192 + 4096 + tid*8]); }

  // ---- fragment read offsets (swizzled), ushort units ----
  const int fr = lane & 15, q = lane >> 4;
  const int c80 = ((q)     ^ (fr & 7)) << 3;   // kk=0 slice
  const int c81 = ((4 + q) ^ (fr & 7)) << 3;   // kk=1 slice
  const int aoff0 = wr * 8192 + fr * 64 + c80;
  const int aoff1 = wr * 8192 + fr * 64 + c81;
  const int boff0 = 16384 + (wc * 16 + fr) * 64 + c80;
  const int boff1 = 16384 + (wc * 16 + fr) * 64 + c81;

#define RD_A(dd, mq) { _Pragma("unroll") for (int m = 0; m < 4; m++) { \
    aFk0[m] = *(const bf16x8*)(&lds2[dd][aoff0 + (mq)*4096 + m*1024]); \
    aFk1[m] = *(const bf16x8*)(&lds2[dd][aoff1 + (mq)*4096 + m*1024]); } }
#define RD_B(dd, nq, b_k0, b_k1) { _Pragma("unroll") for (int n2 = 0; n2 < 2; n2++) { \
    b_k0[n2] = *(const bf16x8*)(&lds2[dd][boff0 + (nq)*8192 + n2*4096]); \
    b_k1[n2] = *(const bf16x8*)(&lds2[dd][boff1 + (nq)*8192 + n2*4096]); } }
#define MF(mq, nq, b_k0, b_k1) { \
  __builtin_amdgcn_s_setprio(1); \
  _Pragma("unroll") for (int m = 0; m < 4; m++) \
    _Pragma("unroll") for (int n2 = 0; n2 < 2; n2++) \
      acc[(mq)*4+m][(nq)*2+n2] = __builtin_amdgcn_mfma_f32_16x16x32_bf16(aFk0[m], b_k0[n2], acc[(mq)*4+m][(nq)*2+n2], 0, 0, 0); \
  _Pragma("unroll") for (int m = 0; m < 4; m++) \
    _Pragma("unroll") for (int n2 = 0; n2 < 2; n2++) \
      acc[(mq)*4+m][(nq)*2+n2] = __builtin_amdgcn_mfma_f32_16x16x32_bf16(aFk1[m], b_k1[n2], acc[(mq)*4+m][(nq)*2+n2], 0, 0, 0); \
  __builtin_amdgcn_s_setprio(0); \
  __builtin_amdgcn_sched_barrier(0); }

  f32x4 acc[8][4] = {};   // [am = mq*4+m][gate = nq*2+n2]
  bf16x8 aFk0[4], aFk1[4], b0k0[2], b0k1[2], b1k0[2], b1k1[2];

  // ---- prologue: stage tile 0 fully; A0,A1,B0 landed (B1 may fly) ----
  STG_AH(0, 0, 0); STG_AH(0, 0, 1); STG_BH(0, 0, 0); STG_BH(0, 0, 1);
  VMW(2); BAR();

  for (int t = 0; t < NKT; ++t) {
    const int d = t & 1, dn = d ^ 1;
    const bool more = (t < NKT - 1);
    // p0: (mq0, nq0) — reads A[mq0] (8) + B[nq0] (4)
    RD_A(d, 0); RD_B(d, 0, b0k0, b0k1);
    if (more) STG_AH(dn, t + 1, 0);
    BAR(); LGKM0();
    MF(0, 0, b0k0, b0k1);
    if (more) { VMW(2); } else { VMW(0); }   // publish B1(t)
    BAR();
    // p1: (mq0, nq1) — reads B[nq1] (4)
    RD_B(d, 1, b1k0, b1k1);
    if (more) STG_AH(dn, t + 1, 1);
    BAR(); LGKM0();
    MF(0, 1, b1k0, b1k1);
    BAR();
    // p2: (mq1, nq1) — reads A[mq1] (8)
    RD_A(d, 1);
    if (more) STG_BH(dn, t + 1, 0);
    BAR(); LGKM0();
    MF(1, 1, b1k0, b1k1);
    BAR();
    // p3: (mq1, nq0) — regs only
    if (more) STG_BH(dn, t + 1, 1);
    BAR();
    MF(1, 0, b0k0, b0k1);
    VMW(2);                                   // publish A0,A1,B0 of t+1
    BAR();
  }

  // ---- fused LSTM epilogue ----
  const int cr = (lane >> 4) * 4;
  const int cc = lane & 15;
  const int j = bCol * 64 + wc * 16 + cc;       // 0..1023
#pragma unroll
  for (int m = 0; m < 8; m++) {
#pragma unroll
    for (int r = 0; r < 4; r++) {
      const int row = bRow * 256 + wr * 128 + m * 16 + cr + r;
      float iv = sigm(acc[m][0][r] + bl[j]);
      float fv = sigm(acc[m][1][r] + bl[1024 + j]);
      float ov = sigm(acc[m][2][r] + bl[2048 + j]);
      float gv = tanhf(acc[m][3][r] + bl[3072 + j]);
      float cn = fv * c_cur[(long)row * HSZ + j] + iv * gv;
      float hn = ov * tanhf(cn);
      out[(long)row * HSZ + j] = hn;                         // h_next
      out[(long)B_ROWS * HSZ + (long)row * HSZ + j] = cn;    // c_next
    }
  }
}

// ---------- launch ----------
extern "C" void kernel_launch(void* const* d_in, const int* in_sizes, int n_in,
                              void* d_out, int out_size, void* d_ws, size_t ws_size,
                              hipStream_t stream) {
  const float* inp = (const float*)d_in[0];   // input_tensor [8192][1025]
  const float* h   = (const float*)d_in[1];   // h_cur
  const float* c   = (const float*)d_in[2];   // c_cur
  const float* Wl  = (const float*)d_in[3];   // W_layers [4096][2048]
  const float* bl  = (const float*)d_in[4];   // b_layers [4096]
  const float* Wd  = (const float*)d_in[5];   // W_desc [1024][1024]
  const float* bd  = (const float*)d_in[6];   // b_desc [1024]

  char* ws = (char*)d_ws;
  unsigned short* comb = (unsigned short*)(ws);               // 33,554,432 B
  unsigned short* Wlb  = (unsigned short*)(ws + 33554432);    // 16,777,216 B
  unsigned short* hb   = (unsigned short*)(ws + 50331648);    // 16,777,216 B
  unsigned short* Wdb  = (unsigned short*)(ws + 67108864);    //  2,097,152 B
  float*          Tm1  = (float*)(ws + 69206016);             //     32,768 B
  float*          out  = (float*)d_out;                       // f32 outputs

  hipLaunchKernelGGL(k_convert, dim3(2048), dim3(256), 0, stream,
                     inp, h, Wl, Wd, comb, Wlb, hb, Wdb, Tm1);
  hipLaunchKernelGGL(k_gemm1, dim3(64, 8), dim3(256), 0, stream,
                     hb, Wdb, h, bd, Tm1, comb);
  hipLaunchKernelGGL(k_gemm2_q, dim3(512), dim3(512), 0, stream,
                     comb, Wlb, bl, c, out);
}